// Round 2
// baseline (2865.521 us; speedup 1.0000x reference)
//
#include <hip/hip_runtime.h>
#include <cstdint>

// ---------------- common types / helpers ----------------
typedef short s16x8 __attribute__((ext_vector_type(8)));
typedef __bf16 b16x8 __attribute__((ext_vector_type(8)));
typedef float f32x4 __attribute__((ext_vector_type(4)));

#define TSEQ 2048
#define EDIM 1024

__device__ __forceinline__ short f2bf(float x) {  // RTNE float->bf16
  unsigned u = __float_as_uint(x);
  unsigned r = (u + 0x7FFFu + ((u >> 16) & 1u)) >> 16;
  return (short)r;
}

__device__ __forceinline__ f32x4 mfma16(s16x8 a, s16x8 b, f32x4 c) {
  return __builtin_amdgcn_mfma_f32_16x16x32_bf16(
      __builtin_bit_cast(b16x8, a), __builtin_bit_cast(b16x8, b), c, 0, 0, 0);
}

// ---------------- weight transpose + fp32->bf16 convert ----------------
// W[K][N] fp32 -> WT[N][K] bf16. grid = (N/32)*(K/32) blocks of 256.
__global__ __launch_bounds__(256) void cvtT(
    const float* __restrict__ W, short* __restrict__ WT, int K, int N) {
  int t = blockIdx.x;
  const int tn = N >> 5;
  const int bn = (t % tn) << 5, bk = (t / tn) << 5;
  __shared__ float tile[32][33];
  const int tx = threadIdx.x & 31, ty = threadIdx.x >> 5;  // ty 0..7
#pragma unroll
  for (int i = 0; i < 4; ++i)
    tile[ty + i * 8][tx] = W[(size_t)(bk + ty + i * 8) * N + bn + tx];
  __syncthreads();
#pragma unroll
  for (int i = 0; i < 4; ++i)
    WT[(size_t)(bn + ty + i * 8) * K + bk + tx] = f2bf(tile[tx][ty + i * 8]);
}

// ---------------- layernorm: fp32 in -> bf16 out ----------------
__global__ __launch_bounds__(256) void ln_kernel(
    const float* __restrict__ h, const float* __restrict__ w,
    const float* __restrict__ b, short* __restrict__ y) {
  const int row = blockIdx.x, tid = threadIdx.x;
  const float4 v = ((const float4*)(h + (size_t)row * EDIM))[tid];
  float s = v.x + v.y + v.z + v.w;
  float s2 = v.x * v.x + v.y * v.y + v.z * v.z + v.w * v.w;
#pragma unroll
  for (int off = 1; off < 64; off <<= 1) {
    s += __shfl_xor(s, off, 64);
    s2 += __shfl_xor(s2, off, 64);
  }
  __shared__ float red[8];
  const int wave = tid >> 6, lane = tid & 63;
  if (lane == 0) { red[wave] = s; red[4 + wave] = s2; }
  __syncthreads();
  s = red[0] + red[1] + red[2] + red[3];
  s2 = red[4] + red[5] + red[6] + red[7];
  const float mu = s * (1.f / EDIM);
  const float var = s2 * (1.f / EDIM) - mu * mu;
  const float rstd = rsqrtf(var + 1e-5f);
  const float4 wv = ((const float4*)w)[tid];
  const float4 bv = ((const float4*)b)[tid];
  short4 o = make_short4(f2bf((v.x - mu) * rstd * wv.x + bv.x),
                         f2bf((v.y - mu) * rstd * wv.y + bv.y),
                         f2bf((v.z - mu) * rstd * wv.z + bv.z),
                         f2bf((v.w - mu) * rstd * wv.w + bv.w));
  ((short4*)(y + (size_t)row * EDIM))[tid] = o;
}

// ---------------- GEMM: C[M,N] = A[M,K](bf16) * BT[N,K]^T + bias ----------------
// 128x128 tile, BK=32, 4 waves of 64x64, explicit vector staging (no
// global_load_lds this round -- correctness first, re-add as A/B later).
// EPI 0: QKV split (cols<2048 -> qk bf16 row-major; cols>=2048 -> V^T scatter)
// EPI 1: += resid, fp32 out    EPI 2: gelu(tanh approx), bf16 out
template <int EPI>
__global__ __launch_bounds__(256, 2) void gemm_bt(
    const short* __restrict__ A, const short* __restrict__ BT,
    const float* __restrict__ bias, short* __restrict__ out_bf,
    short* __restrict__ vt, float* __restrict__ out_f,
    const float* __restrict__ resid, int M, int N, int K) {
  __shared__ __align__(16) short As[128 * 32];
  __shared__ __align__(16) short Bs[128 * 32];
  const int tid = threadIdx.x;
  const int wave = tid >> 6, lane = tid & 63;
  const int quad = lane >> 4, l16 = lane & 15;
  const int wr = (wave >> 1) * 64, wc = (wave & 1) * 64;
  const int m0 = blockIdx.y * 128, n0 = blockIdx.x * 128;

  const int srow = tid >> 2, scol = (tid & 3) * 8;  // staging: 4 x 16B chunks/row
  const short* Ag = A + (size_t)(m0 + srow) * K + scol;
  const short* Bg = BT + (size_t)(n0 + srow) * K + scol;

  f32x4 acc[4][4] = {};
  for (int k0 = 0; k0 < K; k0 += 32) {
    const s16x8 a0 = *(const s16x8*)(Ag + k0);
    const s16x8 a1 = *(const s16x8*)(Ag + (size_t)64 * K + k0);
    const s16x8 b0 = *(const s16x8*)(Bg + k0);
    const s16x8 b1 = *(const s16x8*)(Bg + (size_t)64 * K + k0);
    __syncthreads();  // prev iteration's fragment reads complete
    *(s16x8*)&As[srow * 32 + scol] = a0;
    *(s16x8*)&As[(64 + srow) * 32 + scol] = a1;
    *(s16x8*)&Bs[srow * 32 + scol] = b0;
    *(s16x8*)&Bs[(64 + srow) * 32 + scol] = b1;
    __syncthreads();  // stores visible to all waves
    s16x8 af[4], bfr[4];
#pragma unroll
    for (int i = 0; i < 4; ++i)
      af[i] = *(const s16x8*)&As[(wr + i * 16 + l16) * 32 + quad * 8];
#pragma unroll
    for (int i = 0; i < 4; ++i)
      bfr[i] = *(const s16x8*)&Bs[(wc + i * 16 + l16) * 32 + quad * 8];
#pragma unroll
    for (int mi = 0; mi < 4; ++mi)
#pragma unroll
      for (int ni = 0; ni < 4; ++ni)
        acc[mi][ni] = mfma16(af[mi], bfr[ni], acc[mi][ni]);
  }

#pragma unroll
  for (int mi = 0; mi < 4; ++mi) {
#pragma unroll
    for (int ni = 0; ni < 4; ++ni) {
      const int col = n0 + wc + ni * 16 + l16;
      const float bv = bias[col];
#pragma unroll
      for (int r = 0; r < 4; ++r) {
        const int row = m0 + wr + mi * 16 + quad * 4 + r;
        float v = acc[mi][ni][r] + bv;
        if (EPI == 1) {
          const size_t idx = (size_t)row * N + col;
          out_f[idx] = v + resid[idx];
        } else if (EPI == 2) {
          const float u = 0.7978845608028654f * (v + 0.044715f * v * v * v);
          out_bf[(size_t)row * N + col] = f2bf(0.5f * v * (1.f + tanhf(u)));
        } else {  // QKV
          if (col < 2048)
            out_bf[(size_t)row * 2048 + col] = f2bf(v);
          else
            vt[(size_t)(col - 2048) * TSEQ + row] = f2bf(v);  // V^T [1024][T]
        }
      }
    }
  }
}

// ---------------- fused causal flash attention ----------------
// grid (qtile=16, head=16), block 256 (4 waves). Waves split the 128 q rows
// (32 each) so online-softmax state is wave-private. K and V^T fragments are
// loaded directly from global (k-contiguous). P goes C-layout -> LDS -> A-layout.
__global__ __launch_bounds__(256, 2) void attn_fused(
    const short* __restrict__ qk,  // [T][2048]: q cols h*64.., k cols 1024+h*64..
    const short* __restrict__ vt,  // [1024][T] = V^T rows (h*64+dh)
    short* __restrict__ aout) {    // [T][1024] bf16
  const int head = blockIdx.y;
  const int qt = blockIdx.x;
  const int tid = threadIdx.x;
  const int wave = tid >> 6, lane = tid & 63;
  const int quad = lane >> 4, l16 = lane & 15;
  const int qbase = qt * 128 + wave * 32;

  __shared__ __align__(16) short Ps[4][32 * 136];  // per-wave, padded (+8)
  short* ps = Ps[wave];

  s16x8 qf[2][2];
#pragma unroll
  for (int mi = 0; mi < 2; ++mi)
#pragma unroll
    for (int ks = 0; ks < 2; ++ks)
      qf[mi][ks] = *(const s16x8*)&qk[(size_t)(qbase + mi * 16 + l16) * 2048 +
                                      head * 64 + ks * 32 + quad * 8];

  const float scale = 0.125f;  // 1/sqrt(64)
  float mrow[2][4], lrow[2][4];
  f32x4 oacc[2][4] = {};
#pragma unroll
  for (int mi = 0; mi < 2; ++mi)
#pragma unroll
    for (int r = 0; r < 4; ++r) { mrow[mi][r] = -1e30f; lrow[mi][r] = 0.f; }

  for (int kt = 0; kt <= qt; ++kt) {
    const int k0 = kt * 128;
    f32x4 s[2][8] = {};
#pragma unroll
    for (int ni = 0; ni < 8; ++ni) {
      const size_t krow = (size_t)(k0 + ni * 16 + l16) * 2048 + 1024 + head * 64;
      s16x8 kf0 = *(const s16x8*)&qk[krow + quad * 8];
      s16x8 kf1 = *(const s16x8*)&qk[krow + 32 + quad * 8];
#pragma unroll
      for (int mi = 0; mi < 2; ++mi) {
        s[mi][ni] = mfma16(qf[mi][0], kf0, s[mi][ni]);
        s[mi][ni] = mfma16(qf[mi][1], kf1, s[mi][ni]);
      }
    }
    const bool diag = (kt == qt);
    float rmax[2][4];
#pragma unroll
    for (int mi = 0; mi < 2; ++mi)
#pragma unroll
      for (int r = 0; r < 4; ++r) rmax[mi][r] = -1e30f;
#pragma unroll
    for (int mi = 0; mi < 2; ++mi)
#pragma unroll
      for (int ni = 0; ni < 8; ++ni)
#pragma unroll
        for (int r = 0; r < 4; ++r) {
          float v = s[mi][ni][r] * scale;
          if (diag) {
            const int qa = qbase + mi * 16 + quad * 4 + r;
            const int ka = k0 + ni * 16 + l16;
            if (ka > qa) v = -1e30f;
          }
          s[mi][ni][r] = v;
          rmax[mi][r] = fmaxf(rmax[mi][r], v);
        }
    // reduce row-max across the 16 lanes (l16) holding each row
#pragma unroll
    for (int off = 1; off < 16; off <<= 1)
#pragma unroll
      for (int mi = 0; mi < 2; ++mi)
#pragma unroll
        for (int r = 0; r < 4; ++r)
          rmax[mi][r] = fmaxf(rmax[mi][r], __shfl_xor(rmax[mi][r], off, 64));
    float al[2][4];
#pragma unroll
    for (int mi = 0; mi < 2; ++mi)
#pragma unroll
      for (int r = 0; r < 4; ++r) {
        const float mnew = fmaxf(mrow[mi][r], rmax[mi][r]);
        const float a = __expf(mrow[mi][r] - mnew);
        mrow[mi][r] = mnew;
        lrow[mi][r] *= a;
        al[mi][r] = a;
      }
#pragma unroll
    for (int mi = 0; mi < 2; ++mi)
#pragma unroll
      for (int ni = 0; ni < 4; ++ni)
#pragma unroll
        for (int r = 0; r < 4; ++r) oacc[mi][ni][r] *= al[mi][r];
    float psum[2][4] = {};
#pragma unroll
    for (int mi = 0; mi < 2; ++mi)
#pragma unroll
      for (int ni = 0; ni < 8; ++ni)
#pragma unroll
        for (int r = 0; r < 4; ++r) {
          const float p = __expf(s[mi][ni][r] - mrow[mi][r]);
          psum[mi][r] += p;
          ps[(mi * 16 + quad * 4 + r) * 136 + ni * 16 + l16] = f2bf(p);
        }
    // FIX (round 1 bug): psum holds only this lane's 8 columns -- reduce
    // across the 16 l16 lanes so lrow is the full row sum.
#pragma unroll
    for (int off = 1; off < 16; off <<= 1)
#pragma unroll
      for (int mi = 0; mi < 2; ++mi)
#pragma unroll
        for (int r = 0; r < 4; ++r)
          psum[mi][r] += __shfl_xor(psum[mi][r], off, 64);
#pragma unroll
    for (int mi = 0; mi < 2; ++mi)
#pragma unroll
      for (int r = 0; r < 4; ++r) lrow[mi][r] += psum[mi][r];
    __syncthreads();  // P writes visible before A-layout reads (uniform trip count)
    // P (A-layout from LDS) x V^T (global) -> O
#pragma unroll
    for (int ks = 0; ks < 4; ++ks) {
      s16x8 pa0 = *(const s16x8*)&ps[(0 + l16) * 136 + ks * 32 + quad * 8];
      s16x8 pa1 = *(const s16x8*)&ps[(16 + l16) * 136 + ks * 32 + quad * 8];
#pragma unroll
      for (int ni = 0; ni < 4; ++ni) {
        s16x8 vf = *(const s16x8*)&vt[(size_t)(head * 64 + ni * 16 + l16) * TSEQ +
                                      k0 + ks * 32 + quad * 8];
        oacc[0][ni] = mfma16(pa0, vf, oacc[0][ni]);
        oacc[1][ni] = mfma16(pa1, vf, oacc[1][ni]);
      }
    }
  }
#pragma unroll
  for (int mi = 0; mi < 2; ++mi)
#pragma unroll
    for (int ni = 0; ni < 4; ++ni)
#pragma unroll
      for (int r = 0; r < 4; ++r) {
        const int qa = qbase + mi * 16 + quad * 4 + r;
        aout[(size_t)qa * EDIM + head * 64 + ni * 16 + l16] =
            f2bf(oacc[mi][ni][r] / lrow[mi][r]);
      }
}

// ---------------- launch ----------------
extern "C" void kernel_launch(void* const* d_in, const int* in_sizes, int n_in,
                              void* d_out, int out_size, void* d_ws, size_t ws_size,
                              hipStream_t stream) {
  const float* x     = (const float*)d_in[0];
  const float* ln1w  = (const float*)d_in[1];
  const float* ln1b  = (const float*)d_in[2];
  const float* attw  = (const float*)d_in[3];
  const float* attb  = (const float*)d_in[4];
  const float* projw = (const float*)d_in[5];
  const float* projb = (const float*)d_in[6];
  const float* ln2w  = (const float*)d_in[7];
  const float* ln2b  = (const float*)d_in[8];
  const float* fcw   = (const float*)d_in[9];
  const float* fcb   = (const float*)d_in[10];
  const float* fc2w  = (const float*)d_in[11];
  const float* fc2b  = (const float*)d_in[12];

  // 36 MB pool with liveness-based reuse (round-1 NaN suspect: oversized ws)
  char* ws = (char*)d_ws;
  float* h   = (float*)(ws);               // [0,8)   residual fp32, persistent
  short* y   = (short*)(ws + (8u << 20));  // [8,12)  LN out bf16 / att (reused)
  short* att = (short*)(ws + (8u << 20));  //         att shares y's slot
  short* qkb = (short*)(ws + (12u << 20)); // [12,20) q,k bf16 [T][2048]
  short* vt  = (short*)(ws + (20u << 20)); // [20,24) V^T bf16 [1024][T]
  short* mid = (short*)(ws + (12u << 20)); // [12,28) gelu(fc) bf16 (reuses qkb/vt)
  short* wT  = (short*)(ws + (28u << 20)); // [28,36) JIT-transposed weights

  hipMemcpyAsync(h, x, (size_t)TSEQ * EDIM * 4, hipMemcpyDeviceToDevice, stream);

  for (int l = 0; l < 8; ++l) {
    // ---- attention ----
    ln_kernel<<<TSEQ, 256, 0, stream>>>(h, ln1w + l * 1024, ln1b + l * 1024, y);
    cvtT<<<(3072 / 32) * (1024 / 32), 256, 0, stream>>>(
        attw + (size_t)l * 1024 * 3072, wT, 1024, 3072);
    gemm_bt<0><<<dim3(24, 16), 256, 0, stream>>>(
        y, wT, attb + l * 3072, qkb, vt, nullptr, nullptr, 2048, 3072, 1024);
    attn_fused<<<dim3(16, 16), 256, 0, stream>>>(qkb, vt, att);
    cvtT<<<(1024 / 32) * (1024 / 32), 256, 0, stream>>>(
        projw + (size_t)l * 1024 * 1024, wT, 1024, 1024);
    gemm_bt<1><<<dim3(8, 16), 256, 0, stream>>>(
        att, wT, projb + l * 1024, nullptr, nullptr, h, h, 2048, 1024, 1024);
    // ---- MLP ----
    ln_kernel<<<TSEQ, 256, 0, stream>>>(h, ln2w + l * 1024, ln2b + l * 1024, y);
    cvtT<<<(4096 / 32) * (1024 / 32), 256, 0, stream>>>(
        fcw + (size_t)l * 1024 * 4096, wT, 1024, 4096);
    gemm_bt<2><<<dim3(32, 16), 256, 0, stream>>>(
        y, wT, fcb + l * 4096, mid, nullptr, nullptr, nullptr, 2048, 4096, 1024);
    cvtT<<<(1024 / 32) * (4096 / 32), 256, 0, stream>>>(
        fc2w + (size_t)l * 4096 * 1024, wT, 4096, 1024);
    gemm_bt<1><<<dim3(8, 16), 256, 0, stream>>>(
        mid, wT, fc2b + l * 1024, nullptr, nullptr, h, h, 2048, 1024, 4096);
  }

  hipMemcpyAsync(d_out, h, (size_t)TSEQ * EDIM * 4, hipMemcpyDeviceToDevice, stream);
}

// Round 3
// 2845.909 us; speedup vs baseline: 1.0069x; 1.0069x over previous
//
#include <hip/hip_runtime.h>
#include <cstdint>

// ---------------- common types / helpers ----------------
typedef short s16x8 __attribute__((ext_vector_type(8)));
typedef __bf16 b16x8 __attribute__((ext_vector_type(8)));
typedef float f32x4 __attribute__((ext_vector_type(4)));

#define TSEQ 2048
#define EDIM 1024

__device__ __forceinline__ short f2bf(float x) {  // RTNE float->bf16
  unsigned u = __float_as_uint(x);
  unsigned r = (u + 0x7FFFu + ((u >> 16) & 1u)) >> 16;
  return (short)r;
}

__device__ __forceinline__ f32x4 mfma16(s16x8 a, s16x8 b, f32x4 c) {
  return __builtin_amdgcn_mfma_f32_16x16x32_bf16(
      __builtin_bit_cast(b16x8, a), __builtin_bit_cast(b16x8, b), c, 0, 0, 0);
}

// async global->LDS, 16B/lane; lds base wave-uniform, lane i -> base + i*16
__device__ __forceinline__ void gl_lds16(void* lds, const void* g) {
  __builtin_amdgcn_global_load_lds(
      (const __attribute__((address_space(1))) void*)g,
      (__attribute__((address_space(3))) void*)lds, 16, 0, 0);
}

// ---------------- weight transpose + fp32->bf16 convert ----------------
__global__ __launch_bounds__(256) void cvtT(
    const float* __restrict__ W, short* __restrict__ WT, int K, int N) {
  int t = blockIdx.x;
  const int tn = N >> 5;
  const int bn = (t % tn) << 5, bk = (t / tn) << 5;
  __shared__ float tile[32][33];
  const int tx = threadIdx.x & 31, ty = threadIdx.x >> 5;
#pragma unroll
  for (int i = 0; i < 4; ++i)
    tile[ty + i * 8][tx] = W[(size_t)(bk + ty + i * 8) * N + bn + tx];
  __syncthreads();
#pragma unroll
  for (int i = 0; i < 4; ++i)
    WT[(size_t)(bn + ty + i * 8) * K + bk + tx] = f2bf(tile[tx][ty + i * 8]);
}

// ---------------- layernorm: fp32 in -> bf16 out ----------------
__global__ __launch_bounds__(256) void ln_kernel(
    const float* __restrict__ h, const float* __restrict__ w,
    const float* __restrict__ b, short* __restrict__ y) {
  const int row = blockIdx.x, tid = threadIdx.x;
  const float4 v = ((const float4*)(h + (size_t)row * EDIM))[tid];
  float s = v.x + v.y + v.z + v.w;
  float s2 = v.x * v.x + v.y * v.y + v.z * v.z + v.w * v.w;
#pragma unroll
  for (int off = 1; off < 64; off <<= 1) {
    s += __shfl_xor(s, off, 64);
    s2 += __shfl_xor(s2, off, 64);
  }
  __shared__ float red[8];
  const int wave = tid >> 6, lane = tid & 63;
  if (lane == 0) { red[wave] = s; red[4 + wave] = s2; }
  __syncthreads();
  s = red[0] + red[1] + red[2] + red[3];
  s2 = red[4] + red[5] + red[6] + red[7];
  const float mu = s * (1.f / EDIM);
  const float var = s2 * (1.f / EDIM) - mu * mu;
  const float rstd = rsqrtf(var + 1e-5f);
  const float4 wv = ((const float4*)w)[tid];
  const float4 bv = ((const float4*)b)[tid];
  short4 o = make_short4(f2bf((v.x - mu) * rstd * wv.x + bv.x),
                         f2bf((v.y - mu) * rstd * wv.y + bv.y),
                         f2bf((v.z - mu) * rstd * wv.z + bv.z),
                         f2bf((v.w - mu) * rstd * wv.w + bv.w));
  ((short4*)(y + (size_t)row * EDIM))[tid] = o;
}

// ---------------- GEMM: C[M,N] = A[M,K](bf16) * BT[N,K]^T + bias ----------------
// BMx128 tile, BK=32, 4 waves, global_load_lds 16B staging (m97 structure).
// BM=128: wave tile 64x64 (acc 4x4). BM=64: wave tile 32x64 (acc 2x4) -- used
// for N=1024 GEMMs so the grid covers all 256 CUs.
// EPI 0: QKV split  EPI 1: += resid, fp32 out  EPI 2: gelu, bf16 out
template <int EPI, int BM>
__global__ __launch_bounds__(256, 2) void gemm_bt(
    const short* __restrict__ A, const short* __restrict__ BT,
    const float* __restrict__ bias, short* __restrict__ out_bf,
    short* __restrict__ vt, float* __restrict__ out_f,
    const float* __restrict__ resid, int M, int N, int K) {
  constexpr int WM = BM / 2;    // wave tile rows
  constexpr int NMI = WM / 16;  // acc row count
  __shared__ __align__(16) short As[BM * 32];
  __shared__ __align__(16) short Bs[128 * 32];
  const int tid = threadIdx.x;
  const int wave = tid >> 6, lane = tid & 63;
  const int quad = lane >> 4, l16 = lane & 15;
  const int wr = (wave >> 1) * WM, wc = (wave & 1) * 64;
  const int m0 = blockIdx.y * BM, n0 = blockIdx.x * 128;

  const int srow = tid >> 2, scol = (tid & 3) * 8;  // lane -> (row, 16B chunk)
  const short* Ag = A + (size_t)(m0 + srow) * K + scol;
  const short* Bg = BT + (size_t)(n0 + srow) * K + scol;
  short* As0 = &As[wave * 512];
  short* Bs0 = &Bs[wave * 512];
  short* Bs1 = &Bs[2048 + wave * 512];

  f32x4 acc[NMI][4] = {};
  for (int k0 = 0; k0 < K; k0 += 32) {
    gl_lds16(As0, Ag + k0);
    if (BM == 128) gl_lds16(&As[2048 + wave * 512], Ag + (size_t)64 * K + k0);
    gl_lds16(Bs0, Bg + k0);
    gl_lds16(Bs1, Bg + (size_t)64 * K + k0);
    __syncthreads();
    s16x8 af[NMI], bfr[4];
#pragma unroll
    for (int i = 0; i < NMI; ++i)
      af[i] = *(const s16x8*)&As[(wr + i * 16 + l16) * 32 + quad * 8];
#pragma unroll
    for (int i = 0; i < 4; ++i)
      bfr[i] = *(const s16x8*)&Bs[(wc + i * 16 + l16) * 32 + quad * 8];
#pragma unroll
    for (int mi = 0; mi < NMI; ++mi)
#pragma unroll
      for (int ni = 0; ni < 4; ++ni)
        acc[mi][ni] = mfma16(af[mi], bfr[ni], acc[mi][ni]);
    __syncthreads();
  }

#pragma unroll
  for (int mi = 0; mi < NMI; ++mi) {
#pragma unroll
    for (int ni = 0; ni < 4; ++ni) {
      const int col = n0 + wc + ni * 16 + l16;
      const float bv = bias[col];
#pragma unroll
      for (int r = 0; r < 4; ++r) {
        const int row = m0 + wr + mi * 16 + quad * 4 + r;
        float v = acc[mi][ni][r] + bv;
        if (EPI == 1) {
          const size_t idx = (size_t)row * N + col;
          out_f[idx] = v + resid[idx];
        } else if (EPI == 2) {
          const float u = 0.7978845608028654f * (v + 0.044715f * v * v * v);
          out_bf[(size_t)row * N + col] = f2bf(0.5f * v * (1.f + tanhf(u)));
        } else {  // QKV
          if (col < 2048)
            out_bf[(size_t)row * 2048 + col] = f2bf(v);
          else
            vt[(size_t)(col - 2048) * TSEQ + row] = f2bf(v);  // V^T [1024][T]
        }
      }
    }
  }
}

// ---------------- fused causal flash attention, 1 wave / 16 q-rows ----------------
// grid (128 qtiles, 16 heads) = 2048 single-wave blocks (~8 waves/CU vs 1 before:
// the round-2 kernel was latency-bound at Occupancy 6% / MfmaUtil 2.7%).
// qtile swizzled by head so each CU draws a balanced mix of causal depths.
__global__ __launch_bounds__(64) void attn_fused(
    const short* __restrict__ qk,  // [T][2048]: q cols h*64.., k cols 1024+h*64..
    const short* __restrict__ vt,  // [1024][T] = V^T rows (h*64+dh)
    short* __restrict__ aout) {    // [T][1024] bf16
  const int head = blockIdx.y;
  const int qtile = (blockIdx.x + 8 * blockIdx.y) & 127;
  const int lane = threadIdx.x;
  const int quad = lane >> 4, l16 = lane & 15;
  const int qbase = qtile * 16;
  const int qt_end = qbase >> 7;  // last 128-wide kv tile (causal)

  __shared__ __align__(16) short ps[16 * 136];  // P tile, padded

  s16x8 qf[2];
#pragma unroll
  for (int ks = 0; ks < 2; ++ks)
    qf[ks] = *(const s16x8*)&qk[(size_t)(qbase + l16) * 2048 +
                                head * 64 + ks * 32 + quad * 8];

  const float scale = 0.125f;  // 1/sqrt(64)
  float mrow[4], lrow[4];
  f32x4 oacc[4] = {};
#pragma unroll
  for (int r = 0; r < 4; ++r) { mrow[r] = -1e30f; lrow[r] = 0.f; }

  for (int kt = 0; kt <= qt_end; ++kt) {
    const int k0 = kt * 128;
    f32x4 s[8] = {};
#pragma unroll
    for (int ni = 0; ni < 8; ++ni) {
      const size_t krow = (size_t)(k0 + ni * 16 + l16) * 2048 + 1024 + head * 64;
      s16x8 kf0 = *(const s16x8*)&qk[krow + quad * 8];
      s16x8 kf1 = *(const s16x8*)&qk[krow + 32 + quad * 8];
      s[ni] = mfma16(qf[0], kf0, s[ni]);
      s[ni] = mfma16(qf[1], kf1, s[ni]);
    }
    const bool diag = (kt == qt_end);
    float rmax[4] = {-1e30f, -1e30f, -1e30f, -1e30f};
#pragma unroll
    for (int ni = 0; ni < 8; ++ni)
#pragma unroll
      for (int r = 0; r < 4; ++r) {
        float v = s[ni][r] * scale;
        if (diag) {
          const int qa = qbase + quad * 4 + r;
          const int ka = k0 + ni * 16 + l16;
          if (ka > qa) v = -1e30f;
        }
        s[ni][r] = v;
        rmax[r] = fmaxf(rmax[r], v);
      }
#pragma unroll
    for (int off = 1; off < 16; off <<= 1)
#pragma unroll
      for (int r = 0; r < 4; ++r)
        rmax[r] = fmaxf(rmax[r], __shfl_xor(rmax[r], off, 64));
    float al[4];
#pragma unroll
    for (int r = 0; r < 4; ++r) {
      const float mnew = fmaxf(mrow[r], rmax[r]);
      al[r] = __expf(mrow[r] - mnew);
      mrow[r] = mnew;
      lrow[r] *= al[r];
    }
#pragma unroll
    for (int ni = 0; ni < 4; ++ni)
#pragma unroll
      for (int r = 0; r < 4; ++r) oacc[ni][r] *= al[r];
    float psum[4] = {};
#pragma unroll
    for (int ni = 0; ni < 8; ++ni)
#pragma unroll
      for (int r = 0; r < 4; ++r) {
        const float p = __expf(s[ni][r] - mrow[r]);
        psum[r] += p;
        ps[(quad * 4 + r) * 136 + ni * 16 + l16] = f2bf(p);
      }
#pragma unroll
    for (int off = 1; off < 16; off <<= 1)
#pragma unroll
      for (int r = 0; r < 4; ++r) psum[r] += __shfl_xor(psum[r], off, 64);
#pragma unroll
    for (int r = 0; r < 4; ++r) lrow[r] += psum[r];
    __syncthreads();  // P C-layout writes -> A-layout reads
#pragma unroll
    for (int ks = 0; ks < 4; ++ks) {
      s16x8 pa = *(const s16x8*)&ps[l16 * 136 + ks * 32 + quad * 8];
#pragma unroll
      for (int ni = 0; ni < 4; ++ni) {
        s16x8 vf = *(const s16x8*)&vt[(size_t)(head * 64 + ni * 16 + l16) * TSEQ +
                                      k0 + ks * 32 + quad * 8];
        oacc[ni] = mfma16(pa, vf, oacc[ni]);
      }
    }
    __syncthreads();  // PV reads done before next kt overwrites ps
  }
#pragma unroll
  for (int ni = 0; ni < 4; ++ni)
#pragma unroll
    for (int r = 0; r < 4; ++r) {
      const int qa = qbase + quad * 4 + r;
      aout[(size_t)qa * EDIM + head * 64 + ni * 16 + l16] =
          f2bf(oacc[ni][r] / lrow[r]);
    }
}

// ---------------- launch ----------------
extern "C" void kernel_launch(void* const* d_in, const int* in_sizes, int n_in,
                              void* d_out, int out_size, void* d_ws, size_t ws_size,
                              hipStream_t stream) {
  const float* x     = (const float*)d_in[0];
  const float* ln1w  = (const float*)d_in[1];
  const float* ln1b  = (const float*)d_in[2];
  const float* attw  = (const float*)d_in[3];
  const float* attb  = (const float*)d_in[4];
  const float* projw = (const float*)d_in[5];
  const float* projb = (const float*)d_in[6];
  const float* ln2w  = (const float*)d_in[7];
  const float* ln2b  = (const float*)d_in[8];
  const float* fcw   = (const float*)d_in[9];
  const float* fcb   = (const float*)d_in[10];
  const float* fc2w  = (const float*)d_in[11];
  const float* fc2b  = (const float*)d_in[12];

  // 36 MB pool, liveness-based reuse
  char* ws = (char*)d_ws;
  float* h   = (float*)(ws);               // [0,8)   residual fp32, persistent
  short* y   = (short*)(ws + (8u << 20));  // [8,12)  LN out bf16 / att (reused)
  short* att = (short*)(ws + (8u << 20));
  short* qkb = (short*)(ws + (12u << 20)); // [12,20) q,k bf16 [T][2048]
  short* vt  = (short*)(ws + (20u << 20)); // [20,24) V^T bf16 [1024][T]
  short* mid = (short*)(ws + (12u << 20)); // [12,28) gelu(fc) bf16 (reuses qkb/vt)
  short* wT  = (short*)(ws + (28u << 20)); // [28,36) JIT-transposed weights

  hipMemcpyAsync(h, x, (size_t)TSEQ * EDIM * 4, hipMemcpyDeviceToDevice, stream);

  for (int l = 0; l < 8; ++l) {
    // ---- attention ----
    ln_kernel<<<TSEQ, 256, 0, stream>>>(h, ln1w + l * 1024, ln1b + l * 1024, y);
    cvtT<<<(3072 / 32) * (1024 / 32), 256, 0, stream>>>(
        attw + (size_t)l * 1024 * 3072, wT, 1024, 3072);
    gemm_bt<0, 128><<<dim3(24, 16), 256, 0, stream>>>(
        y, wT, attb + l * 3072, qkb, vt, nullptr, nullptr, 2048, 3072, 1024);
    attn_fused<<<dim3(128, 16), 64, 0, stream>>>(qkb, vt, att);
    cvtT<<<(1024 / 32) * (1024 / 32), 256, 0, stream>>>(
        projw + (size_t)l * 1024 * 1024, wT, 1024, 1024);
    gemm_bt<1, 64><<<dim3(8, 32), 256, 0, stream>>>(
        att, wT, projb + l * 1024, nullptr, nullptr, h, h, 2048, 1024, 1024);
    // ---- MLP ----
    ln_kernel<<<TSEQ, 256, 0, stream>>>(h, ln2w + l * 1024, ln2b + l * 1024, y);
    cvtT<<<(4096 / 32) * (1024 / 32), 256, 0, stream>>>(
        fcw + (size_t)l * 1024 * 4096, wT, 1024, 4096);
    gemm_bt<2, 128><<<dim3(32, 16), 256, 0, stream>>>(
        y, wT, fcb + l * 4096, mid, nullptr, nullptr, nullptr, 2048, 4096, 1024);
    cvtT<<<(1024 / 32) * (4096 / 32), 256, 0, stream>>>(
        fc2w + (size_t)l * 4096 * 1024, wT, 4096, 1024);
    gemm_bt<1, 64><<<dim3(8, 32), 256, 0, stream>>>(
        mid, wT, fc2b + l * 1024, nullptr, nullptr, h, h, 2048, 1024, 4096);
  }

  hipMemcpyAsync(d_out, h, (size_t)TSEQ * EDIM * 4, hipMemcpyDeviceToDevice, stream);
}